// Round 8
// baseline (218.060 us; speedup 1.0000x reference)
//
#include <hip/hip_runtime.h>
#include <math.h>

#define Bn   4
#define CINc 64
#define Hh   160
#define Ww   160
#define Gg   8
#define HW   (Hh * Ww)      // 25600
#define COFF 216

#define OROW 292            // offs row stride (ushorts): 72 units * 4 + 4 pad (146 dw)
#define SMEM_USH (64 * OROW)   // 18688 ushorts = 37376 B; halo (7200) unioned

typedef short bf16x8 __attribute__((ext_vector_type(8)));
typedef float f32x4  __attribute__((ext_vector_type(4)));

static __device__ __forceinline__ unsigned short f2bf(float f) {
    unsigned int u = __float_as_uint(f);
    u = (u + 0x7fffu + ((u >> 16) & 1u)) >> 16;
    return (unsigned short)u;
}
static __device__ __forceinline__ float bf2f(unsigned short s) {
    return __uint_as_float(((unsigned int)s) << 16);
}
static __device__ __forceinline__ float blo(unsigned int u) {
    return __uint_as_float(u << 16);
}
static __device__ __forceinline__ float bhi(unsigned int u) {
    return __uint_as_float(u & 0xffff0000u);
}

// ---------- Prep: transposes + weight repacks (1 launch) --------------------
#define WB 180
__global__ __launch_bounds__(256)
void prep_kernel(const float* __restrict__ feat, const float* __restrict__ x,
                 const float* __restrict__ w_off, const float* __restrict__ w_dcn,
                 unsigned short* __restrict__ featT, unsigned short* __restrict__ xG,
                 unsigned short* __restrict__ wofrag, unsigned short* __restrict__ wfrag) {
    const int blk = blockIdx.x;
    const int t = threadIdx.x;
    if (blk < 1280) {
        __shared__ float tile[CINc][161];
        const int isx = blk >= 640;
        const int rem = isx ? blk - 640 : blk;
        const int b = rem / Hh;
        const int h = rem % Hh;
        const float* src = isx ? x : feat;
        for (int i = t; i < CINc * Ww; i += 256) {
            int ci = i / Ww, w = i % Ww;
            tile[ci][w] = src[(((size_t)b * CINc + ci) * Hh + h) * Ww + w];
        }
        __syncthreads();
        if (isx) {
            for (int i = t; i < CINc * Ww; i += 256) {
                int g = i / (Ww * 8);
                int r = i % (Ww * 8);
                int w = r >> 3, cg = r & 7;
                xG[(((size_t)b * Gg + g) * HW + h * Ww + w) * 8 + cg] = f2bf(tile[g * 8 + cg][w]);
            }
        } else {
            for (int i = t; i < CINc * Ww; i += 256) {
                int w = i / CINc, ci = i % CINc;
                featT[(((size_t)b * Hh + h) * Ww + w) * CINc + ci] = f2bf(tile[ci][w]);
            }
        }
    } else {
        for (int e = (blk - 1280) * 256 + t; e < 147456 + 36864; e += WB * 256) {
            if (e < 147456) {
                // wofrag[kp(9)][ks(2)][mt(16)][lane(64)][j(8)]
                const int j    = e & 7;
                const int lane = (e >> 3) & 63;
                const int rest = e >> 9;          // < 288
                const int mt = rest & 15;
                const int q  = rest >> 4;         // < 18
                const int ks = q & 1;
                const int kp = q >> 1;
                const int co = mt * 16 + (lane & 15);
                const int ci = ks * 32 + (lane >> 4) * 8 + j;
                float v = (co < COFF) ? w_off[(size_t)co * 576 + ci * 9 + kp] : 0.f;
                wofrag[e] = f2bf(v);
            } else {
                // wfrag[ks(18)][mt(4)][lane(64)][j(8)], permuted K = g*72+kk*8+cg
                const int e2   = e - 147456;
                const int j    = e2 & 7;
                const int lane = (e2 >> 3) & 63;
                const int mt   = (e2 >> 9) & 3;
                const int ks   = e2 >> 11;
                const int m = mt * 16 + (lane & 15);
                const int k = ks * 32 + (lane >> 4) * 8 + j;
                const int g = k / 72, r = k % 72;
                const int kk = r >> 3, cg = r & 7;
                const int ci = g * 8 + cg;
                wfrag[e2] = f2bf(w_dcn[((size_t)m * CINc + ci) * 9 + kk]);
            }
        }
    }
}

// ---------- Fused kernel: conv -> LDS offsets -> sample-into-Bfrag -> GEMM --
// block = 8x8 pixel tile, 256 threads (4 waves). 1600 blocks.
// DCN phase: wave wv owns pixels p = wv*16+n (N-split); per ks, lane (n,kg)
// samples unit u = ks*4+kg for pixel p -> that IS its MFMA B-fragment.
__global__ __launch_bounds__(256, 4)
void dcnpack_fused(const unsigned short* __restrict__ featT,
                   const unsigned short* __restrict__ xG,
                   const unsigned short* __restrict__ wofrag,
                   const unsigned short* __restrict__ wfrag,
                   const float* __restrict__ b_off,
                   const float* __restrict__ b_dcn,
                   float* __restrict__ out) {
    __shared__ unsigned short smem[SMEM_USH];
    unsigned short* halo = smem;   // [ry(10)][rx(10)][72] during conv (7200 ush)
    unsigned short* offs = smem;   // [64 pix][OROW] after conv: u*4 + {dy,dx,mask,pad}

    const int b  = blockIdx.z;
    const int h0 = blockIdx.y * 8;
    const int w0 = blockIdx.x * 8;
    const int t  = threadIdx.x;
    const int wv   = t >> 6;
    const int lane = t & 63;
    const int n    = lane & 15;
    const int kg   = lane >> 4;

    // ---- stage halo ----
    for (int task = t; task < 800; task += 256) {
        const int pix = task >> 3, ch = task & 7;
        const int ry = pix / 10, rx = pix % 10;
        const int gh = h0 - 1 + ry, gw = w0 - 1 + rx;
        float4 v = make_float4(0.f, 0.f, 0.f, 0.f);
        if (gh >= 0 && gh < Hh && gw >= 0 && gw < Ww)
            v = *(const float4*)(featT + ((((size_t)b * Hh) + gh) * Ww + gw) * CINc + ch * 8);
        *(float4*)(halo + pix * 72 + ch * 8) = v;
    }
    __syncthreads();

    // ---- conv: M=256(pad 216), N=64, K=576; wave owns mt = wv+4i ----
    const int bbase0 = (((n >> 3) * 10) + (n & 7)) * 72 + kg * 8;
    f32x4 cacc[4][4] = {};
    #pragma unroll
    for (int s = 0; s < 18; ++s) {
        const int kp = s >> 1, ks = s & 1;
        const int ky = kp / 3, kx = kp % 3;
        bf16x8 af[4];
        #pragma unroll
        for (int i = 0; i < 4; ++i)
            af[i] = *(const bf16x8*)(wofrag +
                (((size_t)(kp * 2 + ks) * 16 + wv + 4 * i) * 64 + lane) * 8);
        #pragma unroll
        for (int nt = 0; nt < 4; ++nt) {
            const bf16x8 bfr = *(const bf16x8*)(halo + bbase0 + nt * 1440 +
                                                (ky * 10 + kx) * 72 + ks * 32);
            #pragma unroll
            for (int i = 0; i < 4; ++i)
                cacc[i][nt] = __builtin_amdgcn_mfma_f32_16x16x32_bf16(af[i], bfr, cacc[i][nt], 0, 0, 0);
        }
    }
    __syncthreads();   // all halo reads complete before offs overwrites it

    // ---- conv epilogue: bias (+sigmoid) -> offs 8B records ----
    #pragma unroll
    for (int i = 0; i < 4; ++i) {
        const int mt = wv + 4 * i;
        #pragma unroll
        for (int r = 0; r < 4; ++r) {
            const int co = mt * 16 + kg * 4 + r;
            if (co < COFF) {
                const float bias = b_off[co];
                const int ismask = (co >= 144);
                const int gk = ismask ? (co - 144) : (co >> 1);
                const int type = ismask ? 2 : (co & 1);
                #pragma unroll
                for (int nt = 0; nt < 4; ++nt) {
                    const int p = nt * 16 + n;
                    float v = cacc[i][nt][r] + bias;
                    if (ismask) v = 1.f / (1.f + expf(-v));
                    offs[p * OROW + gk * 4 + type] = f2bf(v);
                }
            }
        }
    }
    __syncthreads();

    // ---- DCN: 18 ks-steps; sample -> B-frag in registers -> 4 MFMA ----
    const int pfix = wv * 16 + n;
    const int hh = h0 + (pfix >> 3);
    const int ww = w0 + (pfix & 7);
    const unsigned short* offrow = offs + pfix * OROW;
    const unsigned short* xbb = xG + (size_t)b * Gg * HW * 8;

    f32x4 dacc[4] = {};
    uint4 gq[4];
    float cf[4];

    auto prep = [&](int ksit, uint4* gqo, float* cfo) {
        const int u = ksit * 4 + kg;          // [0,72) = g*9+k
        const int g = (u * 57) >> 9;          // u/9 for u<72
        const int k = u - 9 * g;
        const int ky = (k * 11) >> 5;         // k/3 for k<9
        const int kx = k - 3 * ky;
        const ushort4 o4 = *(const ushort4*)(offrow + u * 4);
        const float dy = bf2f(o4.x), dx = bf2f(o4.y), m = bf2f(o4.z);
        const float py  = (float)(hh + ky - 1) + dy;
        const float pxx = (float)(ww + kx - 1) + dx;
        const float y0f = floorf(py), x0f = floorf(pxx);
        const float ly = py - y0f, lx = pxx - x0f;
        const int y0 = (int)y0f, x0i = (int)x0f;
        const int y1 = y0 + 1, x1 = x0i + 1;
        const float vy0 = (y0 >= 0 && y0 < Hh) ? 1.f : 0.f;
        const float vy1 = (y1 >= 0 && y1 < Hh) ? 1.f : 0.f;
        const float vx0 = (x0i >= 0 && x0i < Ww) ? 1.f : 0.f;
        const float vx1 = (x1 >= 0 && x1 < Ww) ? 1.f : 0.f;
        cfo[0] = (1.f - ly) * (1.f - lx) * vy0 * vx0 * m;
        cfo[1] = (1.f - ly) * lx         * vy0 * vx1 * m;
        cfo[2] = ly         * (1.f - lx) * vy1 * vx0 * m;
        cfo[3] = ly         * lx         * vy1 * vx1 * m;
        const int y0c = min(max(y0, 0), Hh - 1), y1c = min(max(y1, 0), Hh - 1);
        const int x0c = min(max(x0i, 0), Ww - 1), x1c = min(max(x1, 0), Ww - 1);
        const unsigned short* xb = xbb + (size_t)g * HW * 8;
        gqo[0] = *(const uint4*)(xb + ((size_t)(y0c * Ww + x0c)) * 8);
        gqo[1] = *(const uint4*)(xb + ((size_t)(y0c * Ww + x1c)) * 8);
        gqo[2] = *(const uint4*)(xb + ((size_t)(y1c * Ww + x0c)) * 8);
        gqo[3] = *(const uint4*)(xb + ((size_t)(y1c * Ww + x1c)) * 8);
    };

    prep(0, gq, cf);
    #pragma unroll 2
    for (int ks = 0; ks < 18; ++ks) {
        bf16x8 af[4];
        #pragma unroll
        for (int mt = 0; mt < 4; ++mt)
            af[mt] = *(const bf16x8*)(wfrag + (((size_t)ks * 4 + mt) * 64 + lane) * 8);

        uint4 gqn[4]; float cfn[4];
        if (ks < 17) prep(ks + 1, gqn, cfn);   // issue next iter's LDS+gathers early

        const unsigned int a0[4] = {gq[0].x, gq[0].y, gq[0].z, gq[0].w};
        const unsigned int a1[4] = {gq[1].x, gq[1].y, gq[1].z, gq[1].w};
        const unsigned int a2[4] = {gq[2].x, gq[2].y, gq[2].z, gq[2].w};
        const unsigned int a3[4] = {gq[3].x, gq[3].y, gq[3].z, gq[3].w};
        union { unsigned int u[4]; bf16x8 v; } pk;
        #pragma unroll
        for (int j = 0; j < 4; ++j) {
            const float vl = cf[0] * blo(a0[j]) + cf[1] * blo(a1[j])
                           + cf[2] * blo(a2[j]) + cf[3] * blo(a3[j]);
            const float vh = cf[0] * bhi(a0[j]) + cf[1] * bhi(a1[j])
                           + cf[2] * bhi(a2[j]) + cf[3] * bhi(a3[j]);
            // pack (trunc-to-bf16): [vl.hi16 | vh.hi16]
            pk.u[j] = __builtin_amdgcn_perm(__float_as_uint(vh), __float_as_uint(vl), 0x07060302u);
        }
        #pragma unroll
        for (int mt = 0; mt < 4; ++mt)
            dacc[mt] = __builtin_amdgcn_mfma_f32_16x16x32_bf16(af[mt], pk.v, dacc[mt], 0, 0, 0);

        if (ks < 17) {
            #pragma unroll
            for (int i2 = 0; i2 < 4; ++i2) { gq[i2] = gqn[i2]; cf[i2] = cfn[i2]; }
        }
    }

    // ---- epilogue: C/D col=lane&15 -> pixel p; row=kg*4+r within m-tile ----
    #pragma unroll
    for (int mt = 0; mt < 4; ++mt) {
        #pragma unroll
        for (int r = 0; r < 4; ++r) {
            const int o = mt * 16 + kg * 4 + r;
            out[((size_t)b * CINc + o) * HW + hh * Ww + ww] = dacc[mt][r] + b_dcn[o];
        }
    }
}

extern "C" void kernel_launch(void* const* d_in, const int* in_sizes, int n_in,
                              void* d_out, int out_size, void* d_ws, size_t ws_size,
                              hipStream_t stream) {
    const float* x     = (const float*)d_in[0];
    const float* feat  = (const float*)d_in[1];
    const float* w_off = (const float*)d_in[2];
    const float* b_off = (const float*)d_in[3];
    const float* w_dcn = (const float*)d_in[4];
    const float* b_dcn = (const float*)d_in[5];
    float* out = (float*)d_out;

    unsigned short* featT  = (unsigned short*)d_ws;                // 6,553,600
    unsigned short* xG     = featT + (size_t)Bn * HW * CINc;       // 6,553,600
    unsigned short* wofrag = xG + (size_t)Bn * HW * CINc;          // 147,456
    unsigned short* wfrag  = wofrag + (size_t)147456;              // 36,864

    prep_kernel<<<dim3(1280 + WB), 256, 0, stream>>>(
        feat, x, w_off, w_dcn, featT, xG, wofrag, wfrag);
    dcnpack_fused<<<dim3(Ww / 8, Hh / 8, Bn), 256, 0, stream>>>(
        featT, xG, wofrag, wfrag, b_off, b_dcn, out);
}